// Round 13
// baseline (257.697 us; speedup 1.0000x reference)
//
#include <hip/hip_runtime.h>
#include <math.h>

#define NB    16        // batch
#define NC    25        // channels
#define HW    65536     // 256*256
#define CHW   (NC * HW)
#define EPSF  1e-8f
#define TPB   256       // 4 waves, 1 px per thread
#define PXB   256       // pixels per block
#define NBLK  (NB * (HW / PXB))   // 4096 blocks
#define NSTR  64        // accumulator stripes (parallel atomic chains)
#define SACC  64        // floats per stripe
#define PRB   2048      // probe blocks

__device__ __forceinline__ float wave_reduce(float v) {
#pragma unroll
    for (int o = 32; o > 0; o >>= 1) v += __shfl_down(v, o, 64);
    return v;
}

// R20: DIAGNOSTIC ROUND. Ten structurally different kernels (R7..R19) all
// measure ~75us / 2.8 TB/s effective, with L3-warm == HBM-cold, and the
// last three rounds prove the compiler story is not closable (even 50
// volatile-asm loads + value fences leave VGPR_Count=32). Remaining
// hypotheses: H-pattern (50 x 256KB-strided streams cap at ~2.8 TB/s on
// the CU->L2->L3 path no matter the software) vs H-environment (ANY read
// of these harness buffers caps at ~2.8 TB/s -> we have been at the
// roofline since R7). They imply opposite next moves, so this round adds
// a pure memcpy-shaped probe: grid-strided coalesced float4 linear
// read-reduce of both input tensors (210MB), full occupancy, no atomics,
// launched AFTER main+fin (perturbs nothing; rocprof times it as its own
// dispatch). Probe dur ~33-45us => pattern is the wall (restructure next).
// Probe dur ~70-80us => environment roofline (declare it).
// Main kernel kept byte-identical to R19 (known 75us) -- single variable.
__global__ __launch_bounds__(TPB) void yolo_main(const float* __restrict__ outputs,
                                                 const float* __restrict__ labels,
                                                 float* __restrict__ acc) {
    const int wv   = threadIdx.x >> 6;
    const int lane = threadIdx.x & 63;
    const int b    = blockIdx.x >> 8;                      // image
    const int px   = ((blockIdx.x & 255) << 8) + threadIdx.x;

    // byte offset of this thread's channel-0 element (same for both tensors)
    unsigned voff = (unsigned)(((size_t)b * CHW + px) * sizeof(float));

    // ---- 50 loads issued back-to-back (volatile asm, fixed mutual order)
    float o[NC], l[NC];
#pragma unroll
    for (int c = 0; c < NC; ++c) {
        asm volatile("global_load_dword %0, %1, %2"
                     : "=v"(o[c]) : "v"(voff), "s"(outputs));
        asm volatile("global_load_dword %0, %1, %2"
                     : "=v"(l[c]) : "v"(voff), "s"(labels));
        voff += HW * sizeof(float);          // next channel plane (+256KB)
    }
    asm volatile("s_waitcnt vmcnt(0)");
#pragma unroll
    for (int c = 0; c < NC; ++c) {
        asm volatile("" : "+v"(o[c]));
        asm volatile("" : "+v"(l[c]));
    }

    // ---- channel 0: BCE + F1 counters
    const float xv = o[0], yv = l[0];
    float xc = fminf(fmaxf(xv,        EPSF), 1.0f - EPSF);
    float x1 = fminf(fmaxf(1.0f - xv, EPSF), 1.0f - EPSF);
    float obj = -yv * (1.0f - xc) * __logf(xc)
                - (1.0f - yv) * (1.0f - x1) * __logf(x1);
    const float p  = (xv > 0.5f) ? 1.f : 0.f;
    const float yt = (yv > 0.5f) ? 1.f : 0.f;
    float tp = p * yt;
    float fp = p * (1.f - yt);
    float fn = (1.f - p) * yt;

    // ---- channels 1..4: size / offset L1 (weighted by y)
    float szs  = yv * (fabsf(o[1] - l[1]) + fabsf(o[2] - l[2]));
    float offs = yv * (fabsf(o[3] - l[3]) + fabsf(o[4] - l[4]));

    // ---- channels 5..24: argmax(labels) carrying outputs
    // ascending c + strict '>' = argmax first-index tie-break
    float vmax = -1.0f, vout = 0.0f;
#pragma unroll
    for (int c = 5; c < NC; ++c) {
        if (l[c] > vmax) { vmax = l[c]; vout = o[c]; }
    }
    float cls = yv * (-vout);

    // ---- block reduction: 7 values
    obj  = wave_reduce(obj);
    szs  = wave_reduce(szs);
    offs = wave_reduce(offs);
    cls  = wave_reduce(cls);
    tp   = wave_reduce(tp);
    fp   = wave_reduce(fp);
    fn   = wave_reduce(fn);

    __shared__ float sm[TPB / 64][7];
    if (lane == 0) {
        sm[wv][0] = obj;  sm[wv][1] = szs; sm[wv][2] = offs;
        sm[wv][3] = cls;  sm[wv][4] = tp;  sm[wv][5] = fp;  sm[wv][6] = fn;
    }
    __syncthreads();
    if (threadIdx.x < 7) {
        float s = 0.f;
#pragma unroll
        for (int w = 0; w < TPB / 64; ++w) s += sm[w][threadIdx.x];
        // striped accumulators: 64 parallel short atomic chains (R13 win)
        float* st = acc + (size_t)(blockIdx.x & (NSTR - 1)) * SACC;
        if (threadIdx.x < 4) atomicAdd(st + threadIdx.x, s);
        else                 atomicAdd(st + 4 + 3 * b + (threadIdx.x - 4), s);
    }
}

__global__ void yolo_fin(const float* __restrict__ acc, float* __restrict__ out) {
    const int t = threadIdx.x;                // 64 threads, 1 wave
    __shared__ float fin[52];
    if (t < 52) {
        float s = 0.f;
#pragma unroll
        for (int st = 0; st < NSTR; ++st) s += acc[st * SACC + t];
        fin[t] = s;
    }
    __syncthreads();
    if (t == 0) {
        float objT = fin[0];
        float szT  = 0.1f * fin[1];
        float offT = 0.1f * fin[2];
        float clsT = fin[3];
        float f1 = 0.f;
        for (int bb = 0; bb < NB; ++bb) {
            float tpv = fin[4 + 3 * bb], fpv = fin[5 + 3 * bb], fnv = fin[6 + 3 * bb];
            float den = 2.f * tpv + fpv + fnv;
            f1 += (den > 0.f) ? (2.f * tpv) / fmaxf(den, 1.f) : 0.f;
        }
        f1 *= (1.0f / NB);
        out[0] = objT + szT + offT + clsT;
        out[1] = f1;
        out[2] = objT;
        out[3] = szT;
        out[4] = offT;
        out[5] = clsT;
    }
}

// ---- diagnostic: memcpy-shaped linear read of both tensors (210 MB).
// grid-strided float4, coalesced, no atomics; per-block sum -> plain store.
__global__ __launch_bounds__(TPB) void probe_linear(const float* __restrict__ a,
                                                    const float* __restrict__ b,
                                                    float* __restrict__ out) {
    const int wv   = threadIdx.x >> 6;
    const int lane = threadIdx.x & 63;
    const size_t NF4    = (size_t)NB * CHW / 4;     // 6,553,600 float4 per tensor
    const size_t stride = (size_t)gridDim.x * blockDim.x;
    const float4* A = (const float4*)a;
    const float4* B = (const float4*)b;
    float s = 0.f;
    for (size_t i = (size_t)blockIdx.x * blockDim.x + threadIdx.x; i < NF4; i += stride) {
        float4 x = A[i];
        float4 y = B[i];
        s += (x.x + x.y + x.z + x.w) + (y.x + y.y + y.z + y.w);
    }
    s = wave_reduce(s);
    __shared__ float sm[TPB / 64];
    if (lane == 0) sm[wv] = s;
    __syncthreads();
    if (threadIdx.x == 0)
        out[blockIdx.x] = sm[0] + sm[1] + sm[2] + sm[3];
}

extern "C" void kernel_launch(void* const* d_in, const int* in_sizes, int n_in,
                              void* d_out, int out_size, void* d_ws, size_t ws_size,
                              hipStream_t stream) {
    const float* outputs = (const float*)d_in[0];
    const float* labels  = (const float*)d_in[1];
    float* acc   = (float*)d_ws;                       // 16 KB: 64 stripes x 64 floats
    float* probe = (float*)d_ws + NSTR * SACC;         // 8 KB: 2048 per-block sums

    hipMemsetAsync(acc, 0, NSTR * SACC * sizeof(float), stream);
    yolo_main<<<NBLK, TPB, 0, stream>>>(outputs, labels, acc);
    yolo_fin<<<1, 64, 0, stream>>>(acc, (float*)d_out);
    // diagnostic last: measures achievable linear-read BW on these exact
    // buffers without perturbing the scored result
    probe_linear<<<PRB, TPB, 0, stream>>>(outputs, labels, probe);
}

// Round 14
// 225.508 us; speedup vs baseline: 1.1427x; 1.1427x over previous
//
#include <hip/hip_runtime.h>
#include <math.h>

#define NB    16        // batch
#define NC    25        // channels
#define HW    65536     // 256*256
#define CHW   (NC * HW)
#define EPSF  1e-8f
#define TPB   256       // 4 waves
#define PXT   2         // pixels per thread
#define NBLK  ((NB * HW) / (TPB * PXT))   // 2048 blocks = 8/CU = 32 waves/CU
#define NSTR  64        // accumulator stripes (parallel atomic chains)
#define SACC  64        // floats per stripe

__device__ __forceinline__ float wave_reduce(float v) {
#pragma unroll
    for (int o = 32; o > 0; o >>= 1) v += __shfl_down(v, o, 64);
    return v;
}

// R21: probe-shaped main kernel. R20's diagnostic settled 14 rounds of
// ambiguity: a plain HIP grid-strided float4 linear read-reduce of the SAME
// buffers runs at ~5.9 TB/s (35.7us for 210MB), while every kernel that
// walks 10-50 x 256KB-strided streams IN SEQUENCE per wave pins at 2.8 TB/s
// (75us, warm==cold). The environment and compiler are exonerated; the
// per-wave sequential multi-stream pattern is the wall.
// Fix: channel-major restructure with loop-carried state -- the probe's
// exact shape. 2048 blocks x 256 thr x 2px (full 32 waves/CU, probe
// geometry); block owns 512 contiguous px of one image. Peel ch0 (BCE/F1/
// y0), then two RUNTIME-BOUNDED loops (bounds are kernel args so the
// compiler cannot fully unroll back into a 40-stream sequence): c=1..4
// size/offset L1, c=5..24 argmax carrying (vmax,vout). Each iteration =
// 2 dwordx2 loads + few VALU, state ~13 floats -- the compiler pipelines
// this (probe-proven). Ascending c + strict '>' = first-index tie-break.
// Striped accumulators (R13 win) + separate fin kernel stay. Probe removed.
__global__ __launch_bounds__(TPB) void yolo_main(const float* __restrict__ outputs,
                                                 const float* __restrict__ labels,
                                                 float* __restrict__ acc,
                                                 int c_sz_end, int c_cls_end) {
    const int wv   = threadIdx.x >> 6;
    const int lane = threadIdx.x & 63;
    const int g    = (blockIdx.x * TPB + threadIdx.x) * PXT;  // global px pair
    const int b    = g >> 16;              // image (512-px blocks never straddle)
    const int px   = g & (HW - 1);
    const float* op = outputs + (size_t)b * CHW + px;
    const float* lp = labels  + (size_t)b * CHW + px;

    // ---- channel 0 (peeled): BCE + F1 + y0
    float2 x = *(const float2*)op;
    float2 y = *(const float2*)lp;
    float obj = 0.f, tp = 0.f, fp = 0.f, fn = 0.f;
    {
        float xc = fminf(fmaxf(x.x,        EPSF), 1.0f - EPSF);
        float x1 = fminf(fmaxf(1.0f - x.x, EPSF), 1.0f - EPSF);
        obj += -y.x * (1.0f - xc) * __logf(xc)
               - (1.0f - y.x) * (1.0f - x1) * __logf(x1);
        float p  = (x.x > 0.5f) ? 1.f : 0.f;
        float yt = (y.x > 0.5f) ? 1.f : 0.f;
        tp += p * yt; fp += p * (1.f - yt); fn += (1.f - p) * yt;
    }
    {
        float xc = fminf(fmaxf(x.y,        EPSF), 1.0f - EPSF);
        float x1 = fminf(fmaxf(1.0f - x.y, EPSF), 1.0f - EPSF);
        obj += -y.y * (1.0f - xc) * __logf(xc)
               - (1.0f - y.y) * (1.0f - x1) * __logf(x1);
        float p  = (x.y > 0.5f) ? 1.f : 0.f;
        float yt = (y.y > 0.5f) ? 1.f : 0.f;
        tp += p * yt; fp += p * (1.f - yt); fn += (1.f - p) * yt;
    }
    const float y0x = y.x, y0y = y.y;

    // ---- channels 1..4: size/offset L1 (runtime bound -> pipelined loop)
    float szs = 0.f, offs = 0.f;
    for (int c = 1; c < c_sz_end; ++c) {
        float2 oc = *(const float2*)(op + (size_t)c * HW);
        float2 lc = *(const float2*)(lp + (size_t)c * HW);
        float s = y0x * fabsf(oc.x - lc.x) + y0y * fabsf(oc.y - lc.y);
        if (c <= 2) szs += s; else offs += s;
    }

    // ---- channels 5..24: argmax(labels) carrying outputs (runtime bound)
    float vmax0 = -1.f, vout0 = 0.f, vmax1 = -1.f, vout1 = 0.f;
    for (int c = c_sz_end; c < c_cls_end; ++c) {
        float2 lc = *(const float2*)(lp + (size_t)c * HW);
        float2 oc = *(const float2*)(op + (size_t)c * HW);
        if (lc.x > vmax0) { vmax0 = lc.x; vout0 = oc.x; }
        if (lc.y > vmax1) { vmax1 = lc.y; vout1 = oc.y; }
    }
    float cls = y0x * (-vout0) + y0y * (-vout1);

    // ---- block reduction: 7 values
    obj  = wave_reduce(obj);
    szs  = wave_reduce(szs);
    offs = wave_reduce(offs);
    cls  = wave_reduce(cls);
    tp   = wave_reduce(tp);
    fp   = wave_reduce(fp);
    fn   = wave_reduce(fn);

    __shared__ float sm[TPB / 64][7];
    if (lane == 0) {
        sm[wv][0] = obj;  sm[wv][1] = szs; sm[wv][2] = offs;
        sm[wv][3] = cls;  sm[wv][4] = tp;  sm[wv][5] = fp;  sm[wv][6] = fn;
    }
    __syncthreads();
    if (threadIdx.x < 7) {
        float s = 0.f;
#pragma unroll
        for (int w = 0; w < TPB / 64; ++w) s += sm[w][threadIdx.x];
        // striped accumulators: 64 parallel short atomic chains (R13 win)
        float* st = acc + (size_t)(blockIdx.x & (NSTR - 1)) * SACC;
        if (threadIdx.x < 4) atomicAdd(st + threadIdx.x, s);
        else                 atomicAdd(st + 4 + 3 * b + (threadIdx.x - 4), s);
    }
}

__global__ void yolo_fin(const float* __restrict__ acc, float* __restrict__ out) {
    const int t = threadIdx.x;                // 64 threads, 1 wave
    __shared__ float fin[52];
    if (t < 52) {
        float s = 0.f;
#pragma unroll
        for (int st = 0; st < NSTR; ++st) s += acc[st * SACC + t];
        fin[t] = s;
    }
    __syncthreads();
    if (t == 0) {
        float objT = fin[0];
        float szT  = 0.1f * fin[1];
        float offT = 0.1f * fin[2];
        float clsT = fin[3];
        float f1 = 0.f;
        for (int bb = 0; bb < NB; ++bb) {
            float tpv = fin[4 + 3 * bb], fpv = fin[5 + 3 * bb], fnv = fin[6 + 3 * bb];
            float den = 2.f * tpv + fpv + fnv;
            f1 += (den > 0.f) ? (2.f * tpv) / fmaxf(den, 1.f) : 0.f;
        }
        f1 *= (1.0f / NB);
        out[0] = objT + szT + offT + clsT;
        out[1] = f1;
        out[2] = objT;
        out[3] = szT;
        out[4] = offT;
        out[5] = clsT;
    }
}

extern "C" void kernel_launch(void* const* d_in, const int* in_sizes, int n_in,
                              void* d_out, int out_size, void* d_ws, size_t ws_size,
                              hipStream_t stream) {
    const float* outputs = (const float*)d_in[0];
    const float* labels  = (const float*)d_in[1];
    float* acc = (float*)d_ws;   // 64 stripes x 64 floats = 16 KB

    hipMemsetAsync(acc, 0, NSTR * SACC * sizeof(float), stream);
    // runtime loop bounds (5, 25): prevents full unroll of the channel loops
    yolo_main<<<NBLK, TPB, 0, stream>>>(outputs, labels, acc, 5, NC);
    yolo_fin<<<1, 64, 0, stream>>>(acc, (float*)d_out);
}

// Round 15
// 223.872 us; speedup vs baseline: 1.1511x; 1.0073x over previous
//
#include <hip/hip_runtime.h>
#include <math.h>

#define NB    16        // batch
#define NC    25        // channels
#define HW    65536     // 256*256
#define CHW   (NC * HW)
#define EPSF  1e-8f
#define TPB   256       // 4 waves
#define PXT   4         // pixels per thread (float4)
#define NBLK  ((NB * HW) / (TPB * PXT))   // 1024 blocks; 64 blocks/image exactly
#define NSTR  64        // accumulator stripes (parallel atomic chains)
#define SACC  64        // floats per stripe

__device__ __forceinline__ float wave_reduce(float v) {
#pragma unroll
    for (int o = 32; o > 0; o >>= 1) v += __shfl_down(v, o, 64);
    return v;
}

// R22: probe-parity request profile. The model that finally fits ALL rounds:
// throughput ~ outstanding-load-bytes per CU, saturating at ~64KB/CU:
//   probe 64KB -> 5.9 TB/s; R14-19 16KB -> 2.8; R21 32KB (float2, VGPR=12,
//   unpipelined loop) -> 2.5; R11 ~8KB -> 1.25.
// Scheduling tricks to deepen MLP all failed (R9/R10/R13/R15/R16/R18/R19);
// the probe reached 64KB/CU with plain WIDE loads in a simple loop. So:
// reshape to the probe's profile -- 1024 blocks x 256 thr x 4px (float4).
// Peel ch0 (BCE/F1/y0); runtime-bounded size/offset loop; argmax loop over
// c=5..24 manually unrolled x2 so FOUR dwordx4 loads are in flight before
// any consume (ascending c within the pair keeps the argmax first-index
// tie-break). In-flight: 16 waves/CU x 4 x 1KB = 64KB/CU = probe parity.
// Striped accumulators (R13) + separate fin kernel stay.
__global__ __launch_bounds__(TPB) void yolo_main(const float* __restrict__ outputs,
                                                 const float* __restrict__ labels,
                                                 float* __restrict__ acc,
                                                 int c_sz_end, int c_cls_end) {
    const int wv   = threadIdx.x >> 6;
    const int lane = threadIdx.x & 63;
    const int q    = blockIdx.x * TPB + threadIdx.x;   // global pixel-quad
    const int b    = q >> 14;                          // 16384 quads per image
    const int px   = (q & 16383) << 2;
    const float* op = outputs + (size_t)b * CHW + px;
    const float* lp = labels  + (size_t)b * CHW + px;

    // ---- channel 0 (peeled): BCE + F1 + y0
    float4 x  = *(const float4*)op;
    float4 y0 = *(const float4*)lp;
    float obj = 0.f, tp = 0.f, fp = 0.f, fn = 0.f;
    {
        const float xs[4] = {x.x, x.y, x.z, x.w};
        const float ys[4] = {y0.x, y0.y, y0.z, y0.w};
#pragma unroll
        for (int i = 0; i < 4; ++i) {
            float xc = fminf(fmaxf(xs[i],        EPSF), 1.0f - EPSF);
            float x1 = fminf(fmaxf(1.0f - xs[i], EPSF), 1.0f - EPSF);
            obj += -ys[i] * (1.0f - xc) * __logf(xc)
                   - (1.0f - ys[i]) * (1.0f - x1) * __logf(x1);
            float p  = (xs[i] > 0.5f) ? 1.f : 0.f;
            float yt = (ys[i] > 0.5f) ? 1.f : 0.f;
            tp += p * yt; fp += p * (1.f - yt); fn += (1.f - p) * yt;
        }
    }

    // ---- channels 1..4: size/offset L1 (runtime bound)
    float szs = 0.f, offs = 0.f;
    for (int c = 1; c < c_sz_end; ++c) {
        float4 oc = *(const float4*)(op + (size_t)c * HW);
        float4 lc = *(const float4*)(lp + (size_t)c * HW);
        float s = y0.x * fabsf(oc.x - lc.x) + y0.y * fabsf(oc.y - lc.y)
                + y0.z * fabsf(oc.z - lc.z) + y0.w * fabsf(oc.w - lc.w);
        if (c <= 2) szs += s; else offs += s;
    }

    // ---- channels 5..24: argmax(labels) carrying outputs, pair-unrolled:
    // 4 dwordx4 loads in flight per iteration; ascending c order kept.
    float vmax[4] = {-1.f, -1.f, -1.f, -1.f};
    float vout[4] = {0.f, 0.f, 0.f, 0.f};
    int c = c_sz_end;
    for (; c + 1 < c_cls_end; c += 2) {
        float4 la = *(const float4*)(lp + (size_t)c * HW);
        float4 oa = *(const float4*)(op + (size_t)c * HW);
        float4 lb = *(const float4*)(lp + (size_t)(c + 1) * HW);
        float4 ob = *(const float4*)(op + (size_t)(c + 1) * HW);
        const float las[4] = {la.x, la.y, la.z, la.w};
        const float oas[4] = {oa.x, oa.y, oa.z, oa.w};
        const float lbs[4] = {lb.x, lb.y, lb.z, lb.w};
        const float obs[4] = {ob.x, ob.y, ob.z, ob.w};
#pragma unroll
        for (int i = 0; i < 4; ++i) {
            if (las[i] > vmax[i]) { vmax[i] = las[i]; vout[i] = oas[i]; }
            if (lbs[i] > vmax[i]) { vmax[i] = lbs[i]; vout[i] = obs[i]; }
        }
    }
    for (; c < c_cls_end; ++c) {          // tail (empty for 20 channels)
        float4 lc = *(const float4*)(lp + (size_t)c * HW);
        float4 oc = *(const float4*)(op + (size_t)c * HW);
        const float ls[4] = {lc.x, lc.y, lc.z, lc.w};
        const float os[4] = {oc.x, oc.y, oc.z, oc.w};
#pragma unroll
        for (int i = 0; i < 4; ++i) {
            if (ls[i] > vmax[i]) { vmax[i] = ls[i]; vout[i] = os[i]; }
        }
    }
    float cls = y0.x * (-vout[0]) + y0.y * (-vout[1])
              + y0.z * (-vout[2]) + y0.w * (-vout[3]);

    // ---- block reduction: 7 values
    obj  = wave_reduce(obj);
    szs  = wave_reduce(szs);
    offs = wave_reduce(offs);
    cls  = wave_reduce(cls);
    tp   = wave_reduce(tp);
    fp   = wave_reduce(fp);
    fn   = wave_reduce(fn);

    __shared__ float sm[TPB / 64][7];
    if (lane == 0) {
        sm[wv][0] = obj;  sm[wv][1] = szs; sm[wv][2] = offs;
        sm[wv][3] = cls;  sm[wv][4] = tp;  sm[wv][5] = fp;  sm[wv][6] = fn;
    }
    __syncthreads();
    if (threadIdx.x < 7) {
        float s = 0.f;
#pragma unroll
        for (int w = 0; w < TPB / 64; ++w) s += sm[w][threadIdx.x];
        // striped accumulators: 64 parallel short atomic chains (R13 win)
        float* st = acc + (size_t)(blockIdx.x & (NSTR - 1)) * SACC;
        if (threadIdx.x < 4) atomicAdd(st + threadIdx.x, s);
        else                 atomicAdd(st + 4 + 3 * b + (threadIdx.x - 4), s);
    }
}

__global__ void yolo_fin(const float* __restrict__ acc, float* __restrict__ out) {
    const int t = threadIdx.x;                // 64 threads, 1 wave
    __shared__ float fin[52];
    if (t < 52) {
        float s = 0.f;
#pragma unroll
        for (int st = 0; st < NSTR; ++st) s += acc[st * SACC + t];
        fin[t] = s;
    }
    __syncthreads();
    if (t == 0) {
        float objT = fin[0];
        float szT  = 0.1f * fin[1];
        float offT = 0.1f * fin[2];
        float clsT = fin[3];
        float f1 = 0.f;
        for (int bb = 0; bb < NB; ++bb) {
            float tpv = fin[4 + 3 * bb], fpv = fin[5 + 3 * bb], fnv = fin[6 + 3 * bb];
            float den = 2.f * tpv + fpv + fnv;
            f1 += (den > 0.f) ? (2.f * tpv) / fmaxf(den, 1.f) : 0.f;
        }
        f1 *= (1.0f / NB);
        out[0] = objT + szT + offT + clsT;
        out[1] = f1;
        out[2] = objT;
        out[3] = szT;
        out[4] = offT;
        out[5] = clsT;
    }
}

extern "C" void kernel_launch(void* const* d_in, const int* in_sizes, int n_in,
                              void* d_out, int out_size, void* d_ws, size_t ws_size,
                              hipStream_t stream) {
    const float* outputs = (const float*)d_in[0];
    const float* labels  = (const float*)d_in[1];
    float* acc = (float*)d_ws;   // 64 stripes x 64 floats = 16 KB

    hipMemsetAsync(acc, 0, NSTR * SACC * sizeof(float), stream);
    // runtime loop bounds (5, 25) keep the channel loops as loops
    yolo_main<<<NBLK, TPB, 0, stream>>>(outputs, labels, acc, 5, NC);
    yolo_fin<<<1, 64, 0, stream>>>(acc, (float*)d_out);
}